// Round 5
// baseline (379.371 us; speedup 1.0000x reference)
//
#include <hip/hip_runtime.h>
#include <hip/hip_bf16.h>
#include <math.h>

// ---------------------------------------------------------------------------
// SurfNetwork, single-kernel barrier-free. One ray per wave (64 lanes,
// 2 points/lane); 256-thread block = 4 independent rays, zero __syncthreads.
// Weight B-fragments are built in-kernel per lane from W0/W1/W2 (L1/L2-hot
// strided loads, once per block) -- no setup dispatch. A0 LDS holds only
// k0..15 per point (48 B stride); k16/k17 live in a packed sidecar consumed
// by quad-2 lanes at frag assembly (quad 3 = zeros). LDS 38.9 KB/block ->
// 4 blocks/CU. Fetch path is random-64B-line bound (~3.4 TB/s measured
// ceiling across rounds 2-4); this round removes dispatch + occupancy slack.
// Fragment layouts (verified rounds 2-4):
//   A: lane holds A[m=lane&15][k=(lane>>4)*8+j], j=0..7
//   B: lane holds B[k=(lane>>4)*8+j][n=lane&15]
//   C: lane reg r holds C[row=(lane>>4)*4+r][col=lane&15]
// ---------------------------------------------------------------------------

typedef short bf16x8 __attribute__((ext_vector_type(8)));
typedef float floatx4 __attribute__((ext_vector_type(4)));

__device__ inline unsigned short f2b(float f) {  // fp32 -> bf16 RNE
    union { float f; unsigned u; } v; v.f = f;
    unsigned r = v.u + 0x7FFF + ((v.u >> 16) & 1);
    return (unsigned short)(r >> 16);
}
__device__ inline unsigned pk2(float a, float b) {  // two fp32 -> packed bf16x2
    return (unsigned)f2b(a) | ((unsigned)f2b(b) << 16);
}
__device__ inline bf16x8 frag_from(unsigned a, unsigned b, unsigned c, unsigned d) {
    union { unsigned u[4]; bf16x8 v; } t;
    t.u[0] = a; t.u[1] = b; t.u[2] = c; t.u[3] = d;
    return t.v;
}

__global__ __launch_bounds__(256, 4) void surf_main(
    const int*   __restrict__ x,     // (B, 128, 6)
    const float* __restrict__ dvec,  // (B, 16)
    const float* __restrict__ gw,    // (TABLE, 4)
    const float* __restrict__ W0,    // (34, 64)
    const float* __restrict__ b0v,   // (64)
    const float* __restrict__ W1,    // (64, 64)
    const float* __restrict__ b1v,   // (64)
    const float* __restrict__ W2,    // (64, 3)
    const float* __restrict__ b2v,   // (3)
    float* __restrict__ out_sigma,   // (B, 128)
    float* __restrict__ out_color)   // (B, 3)
{
    const int t    = threadIdx.x;
    const int lane = t & 63;
    const int w    = t >> 6;          // wave id = ray slot
    const int l15  = lane & 15;
    const int quad = lane >> 4;
    const size_t ray = (size_t)blockIdx.x * 4 + w;

    // wave-private LDS (no cross-wave sharing; in-order DS pipe, no barriers)
    __shared__ unsigned short A0[4][128 * 24];  // k0..15 bf16/point, 48 B rows
    __shared__ unsigned int   G67[4][128];      // packed (k16,k17) per point
    __shared__ unsigned short HT[4][16 * 72];   // one M-tile of hidden
    __shared__ float cwL[4][128];
    __shared__ float dwL[4][64];

    unsigned short* A0w = A0[w];
    unsigned int*   G67w = G67[w];
    unsigned short* HTw = HT[w];
    float* cww = cwL[w];
    float* dww = dwL[w];

    // ---- x indices first (gathers depend on them) ----
    const int* xp = x + ray * 768 + lane * 12;
    const int4 xa = *(const int4*)(xp);
    const int4 xb = *(const int4*)(xp + 4);
    const int4 xc = *(const int4*)(xp + 8);

    // ---- build weight B-fragments in-registers (fills x-load latency) ----
    const int kq = quad * 8;          // this lane's k base within a 32-K frag
    bf16x8 bw0[4], bw1[8], bw2[2];
    #pragma unroll
    for (int nt = 0; nt < 4; ++nt) {
        const int n = nt * 16 + l15;
        unsigned fr[4];
        #pragma unroll
        for (int jj = 0; jj < 4; ++jj) {
            const int k0 = kq + 2 * jj, k1 = k0 + 1;
            const float f0 = (k0 < 18) ? W0[(16 + k0) * 64 + n] : 0.0f;
            const float f1 = (k1 < 18) ? W0[(16 + k1) * 64 + n] : 0.0f;
            fr[jj] = pk2(f0, f1);
        }
        bw0[nt] = frag_from(fr[0], fr[1], fr[2], fr[3]);
    }
    #pragma unroll
    for (int i = 0; i < 8; ++i) {
        const int kb = (i >> 2) * 32 + kq;
        const int n  = (i & 3) * 16 + l15;
        unsigned fr[4];
        #pragma unroll
        for (int jj = 0; jj < 4; ++jj)
            fr[jj] = pk2(W1[(kb + 2 * jj) * 64 + n], W1[(kb + 2 * jj + 1) * 64 + n]);
        bw1[i] = frag_from(fr[0], fr[1], fr[2], fr[3]);
    }
    #pragma unroll
    for (int s = 0; s < 2; ++s) {
        const int kb = s * 32 + kq;
        unsigned fr[4];
        #pragma unroll
        for (int jj = 0; jj < 4; ++jj) {
            const float f0 = (l15 < 3) ? W2[(kb + 2 * jj) * 3 + l15] : 0.0f;
            const float f1 = (l15 < 3) ? W2[(kb + 2 * jj + 1) * 3 + l15] : 0.0f;
            fr[jj] = pk2(f0, f1);
        }
        bw2[s] = frag_from(fr[0], fr[1], fr[2], fr[3]);
    }
    float b1r[4];
    #pragma unroll
    for (int nt = 0; nt < 4; ++nt) b1r[nt] = b1v[nt * 16 + l15];
    const float b2r = (l15 < 3) ? b2v[l15] : 0.0f;

    // ---- dirW = b0 + d[ray] @ W0dir (col = lane) ----
    {
        float acc = b0v[lane];
        const float* db = dvec + ray * 16;
        #pragma unroll
        for (int i = 0; i < 16; ++i) acc = fmaf(db[i], W0[i * 64 + lane], acc);
        dww[lane] = acc;
    }

    // ---- 12 gathers per lane, all in flight together ----
    float4 g[12];
    g[0]  = *(const float4*)(gw + (size_t)xa.x * 4);
    g[1]  = *(const float4*)(gw + (size_t)xa.y * 4);
    g[2]  = *(const float4*)(gw + (size_t)xa.z * 4);
    g[3]  = *(const float4*)(gw + (size_t)xa.w * 4);
    g[4]  = *(const float4*)(gw + (size_t)xb.x * 4);
    g[5]  = *(const float4*)(gw + (size_t)xb.y * 4);
    g[6]  = *(const float4*)(gw + (size_t)xb.z * 4);
    g[7]  = *(const float4*)(gw + (size_t)xb.w * 4);
    g[8]  = *(const float4*)(gw + (size_t)xc.x * 4);
    g[9]  = *(const float4*)(gw + (size_t)xc.y * 4);
    g[10] = *(const float4*)(gw + (size_t)xc.z * 4);
    g[11] = *(const float4*)(gw + (size_t)xc.w * 4);

    // ---- stage 2 points: sigma product + packed geo -> A0 + G67 ----
    float sig0[2];
    #pragma unroll
    for (int p = 0; p < 2; ++p) {
        const float4* gp = g + 6 * p;
        float s = 1.0f;
        #pragma unroll
        for (int l = 0; l < 6; ++l)
            s *= fminf(fmaxf(gp[l].x, 0.0f), 1.0f);
        sig0[p] = s + 1e-4f;
        const unsigned u0 = pk2(gp[0].y, gp[0].z);
        const unsigned u1 = pk2(gp[0].w, gp[1].y);
        const unsigned u2 = pk2(gp[1].z, gp[1].w);
        const unsigned u3 = pk2(gp[2].y, gp[2].z);
        const unsigned u4 = pk2(gp[2].w, gp[3].y);
        const unsigned u5 = pk2(gp[3].z, gp[3].w);
        const unsigned u6 = pk2(gp[4].y, gp[4].z);
        const unsigned u7 = pk2(gp[4].w, gp[5].y);
        const unsigned u8 = pk2(gp[5].z, gp[5].w);
        const int pt = lane * 2 + p;
        int4* dst = (int4*)(A0w + pt * 24);
        dst[0] = make_int4((int)u0, (int)u1, (int)u2, (int)u3);
        dst[1] = make_int4((int)u4, (int)u5, (int)u6, (int)u7);
        G67w[pt] = u8;
    }

    // ---- sigma normalize + compositing weights (wave-local) ----
    float m = fmaxf(sig0[0], sig0[1]);
    #pragma unroll
    for (int off = 1; off < 64; off <<= 1)
        m = fmaxf(m, __shfl_xor(m, off));
    const float sp0 = sig0[0] / m;
    const float sp1 = sig0[1] / m;
    {
        float2 sv; sv.x = sp0; sv.y = sp1;
        *(float2*)(out_sigma + ray * 128 + lane * 2) = sv;
    }
    const float prev = __shfl_up(sp1, 1);
    const float cw0 = (lane == 0) ? sp0 : (1.0f - prev) * sp0;
    const float cw1 = (1.0f - sp0) * sp1;
    {
        float2 cv; cv.x = cw0; cv.y = cw1;
        *(float2*)(cww + lane * 2) = cv;
    }

    float dw4[4];
    #pragma unroll
    for (int nt = 0; nt < 4; ++nt) dw4[nt] = dww[nt * 16 + l15];

    const bool qlt2 = (quad < 2);
    const bool q2   = (quad == 2);

    // ---- MLP, one M-tile (16 points) at a time ----
    float csum = 0.0f;
    for (int mt = 0; mt < 8; ++mt) {
        const int row = mt * 16 + l15;
        const int4 av = *(const int4*)(A0w + row * 24 + (quad & 1) * 8);
        const unsigned gv = G67w[row];
        bf16x8 a0 = frag_from(qlt2 ? (unsigned)av.x : (q2 ? gv : 0u),
                              qlt2 ? (unsigned)av.y : 0u,
                              qlt2 ? (unsigned)av.z : 0u,
                              qlt2 ? (unsigned)av.w : 0u);

        floatx4 acc0[4];
        #pragma unroll
        for (int nt = 0; nt < 4; ++nt) {
            const float dw = dw4[nt];
            acc0[nt] = (floatx4){dw, dw, dw, dw};
            acc0[nt] = __builtin_amdgcn_mfma_f32_16x16x32_bf16(a0, bw0[nt], acc0[nt], 0, 0, 0);
        }
        #pragma unroll
        for (int nt = 0; nt < 4; ++nt)
            #pragma unroll
            for (int r = 0; r < 4; ++r)
                HTw[(quad * 4 + r) * 72 + nt * 16 + l15] = f2b(fmaxf(acc0[nt][r], 0.0f));

        bf16x8 a1a = *(const bf16x8*)(HTw + l15 * 72 + quad * 8);
        bf16x8 a1b = *(const bf16x8*)(HTw + l15 * 72 + 32 + quad * 8);
        floatx4 acc1[4];
        #pragma unroll
        for (int nt = 0; nt < 4; ++nt) {
            const float bb = b1r[nt];
            acc1[nt] = (floatx4){bb, bb, bb, bb};
            acc1[nt] = __builtin_amdgcn_mfma_f32_16x16x32_bf16(a1a, bw1[nt],     acc1[nt], 0, 0, 0);
            acc1[nt] = __builtin_amdgcn_mfma_f32_16x16x32_bf16(a1b, bw1[4 + nt], acc1[nt], 0, 0, 0);
        }
        #pragma unroll
        for (int nt = 0; nt < 4; ++nt)
            #pragma unroll
            for (int r = 0; r < 4; ++r)
                HTw[(quad * 4 + r) * 72 + nt * 16 + l15] = f2b(fmaxf(acc1[nt][r], 0.0f));

        bf16x8 a2a = *(const bf16x8*)(HTw + l15 * 72 + quad * 8);
        bf16x8 a2b = *(const bf16x8*)(HTw + l15 * 72 + 32 + quad * 8);
        floatx4 acc2 = (floatx4){b2r, b2r, b2r, b2r};
        acc2 = __builtin_amdgcn_mfma_f32_16x16x32_bf16(a2a, bw2[0], acc2, 0, 0, 0);
        acc2 = __builtin_amdgcn_mfma_f32_16x16x32_bf16(a2b, bw2[1], acc2, 0, 0, 0);

        const floatx4 cwq = *(const floatx4*)(cww + mt * 16 + quad * 4);
        #pragma unroll
        for (int r = 0; r < 4; ++r)
            csum += cwq[r] / (1.0f + __expf(-acc2[r]));
    }

    // columns live in l15; fold the 4 quads
    csum += __shfl_xor(csum, 16);
    csum += __shfl_xor(csum, 32);
    if (lane < 3) out_color[ray * 3 + lane] = csum;
}

extern "C" void kernel_launch(void* const* d_in, const int* in_sizes, int n_in,
                              void* d_out, int out_size, void* d_ws, size_t ws_size,
                              hipStream_t stream) {
    const int*   x    = (const int*)d_in[0];
    const float* dvec = (const float*)d_in[1];
    const float* gw   = (const float*)d_in[2];
    const float* W0   = (const float*)d_in[3];
    const float* b0   = (const float*)d_in[4];
    const float* W1   = (const float*)d_in[5];
    const float* b1   = (const float*)d_in[6];
    const float* W2   = (const float*)d_in[7];
    const float* b2   = (const float*)d_in[8];

    const int B = in_sizes[1] / 16;                       // d is (B, 16)
    float* out_sigma = (float*)d_out;                     // (B, 128)
    float* out_color = (float*)d_out + (size_t)B * 128;   // (B, 3)

    surf_main<<<B / 4, 256, 0, stream>>>(x, dvec, gw, W0, b0, W1, b1, W2, b2,
                                         out_sigma, out_color);
}

// Round 6
// 336.543 us; speedup vs baseline: 1.1273x; 1.1273x over previous
//
#include <hip/hip_runtime.h>
#include <math.h>

// ---------------------------------------------------------------------------
// SurfNetwork: hash-grid gather -> sigma product/normalize -> MLP 34->64->64->3
// MLP runs on bf16 MFMA (16x16x32). One ray (128 points) per 512-thread block,
// 8 waves, each wave = one M=16 row tile. Weights pre-packed to B-fragment
// order in d_ws by a setup kernel.
//
// ROOFLINE NOTE (rounds 2-5): FETCH is pinned at the ~766 MB random-64B-line
// floor (12.6M gathers x 64B lines + 50 MB x); four structurally different
// kernels (barrier-coupled, reg-pipelined, wave-per-ray barrier-free,
// in-kernel frag build) all plateau at 3.3-3.5 TB/s on this path. 766 MB at
// 3.5 TB/s = 220 us; this kernel measures 226 us. Random-line fetch path is
// the binding constraint; register prefetch across __syncthreads is
// impossible (barrier lowers to s_waitcnt vmcnt(0)), and persistent weight
// frags + gather registers overflow the VGPR budget (R5 spill).
// Fragment layouts (verified):
//   A: lane holds A[m=lane&15][k=(lane>>4)*8+j], j=0..7
//   B: lane holds B[k=(lane>>4)*8+j][n=lane&15]
//   C: lane reg r holds C[row=(lane>>4)*4+r][col=lane&15]
// ---------------------------------------------------------------------------

typedef short bf16x8 __attribute__((ext_vector_type(8)));
typedef float floatx4 __attribute__((ext_vector_type(4)));

__device__ inline unsigned short f2b(float f) {  // fp32 -> bf16 RNE
    union { float f; unsigned u; } v; v.f = f;
    unsigned r = v.u + 0x7FFF + ((v.u >> 16) & 1);
    return (unsigned short)(r >> 16);
}

// ws layout (bf16/ushort units):
//   [0    .. 2047]  W0geo frags: f = ntile(0..3);          k=geo idx (0..17, pad 32)
//   [2048 .. 6143]  W1    frags: f = kstep*4 + ntile;      k 0..63
//   [6144 .. 7167]  W2    frags: f = kstep(0..1), N=16 pad; n<3 valid
__global__ void build_frags(const float* __restrict__ W0,
                            const float* __restrict__ W1,
                            const float* __restrict__ W2,
                            unsigned short* __restrict__ wsf) {
    int tid = blockIdx.x * blockDim.x + threadIdx.x;
    if (tid >= 7168) return;
    int lane, j, k, n;
    float val;
    if (tid < 2048) {
        int f = tid >> 9, r = tid & 511; lane = r >> 3; j = r & 7;
        k = ((lane >> 4) * 8) + j;            // geo feature index
        n = f * 16 + (lane & 15);
        val = (k < 18) ? W0[(16 + k) * 64 + n] : 0.0f;
    } else if (tid < 6144) {
        int e = tid - 2048;
        int f = e >> 9, r = e & 511; lane = r >> 3; j = r & 7;
        int ks = f >> 2, nt = f & 3;
        k = ks * 32 + ((lane >> 4) * 8) + j;
        n = nt * 16 + (lane & 15);
        val = W1[k * 64 + n];
    } else {
        int e = tid - 6144;
        int f = e >> 9, r = e & 511; lane = r >> 3; j = r & 7;
        k = f * 32 + ((lane >> 4) * 8) + j;
        n = lane & 15;
        val = (n < 3) ? W2[k * 3 + n] : 0.0f;
    }
    wsf[tid] = f2b(val);
}

__global__ __launch_bounds__(512, 4) void surf_main(
    const int*   __restrict__ x,     // (B, 128, 6)
    const float* __restrict__ dvec,  // (B, 16)
    const float* __restrict__ gw,    // (TABLE, 4)
    const float* __restrict__ W0,    // (34, 64)  (dir rows used here)
    const float* __restrict__ b0,    // (64)
    const float* __restrict__ b1,    // (64)
    const float* __restrict__ b2,    // (3)
    const unsigned short* __restrict__ wsf,
    float* __restrict__ out_sigma,   // (B, 128)
    float* __restrict__ out_color)   // (B, 3)
{
    const int b    = blockIdx.x;
    const int t    = threadIdx.x;
    const int lane = t & 63;
    const int w    = t >> 6;         // wave id 0..7 -> rows w*16..w*16+15
    const int l15  = lane & 15;
    const int quad = lane >> 4;

    __shared__ unsigned short A0[128 * 40];  // geo bf16, K padded to 32, stride 40
    __shared__ unsigned short H1[128 * 72];  // hidden bf16, stride 72 (reused for h2)
    __shared__ float s_sigl[768];            // clipped level densities, x memory order
    __shared__ float s_dirW[64];             // b0 + d[b] @ W0[0:16,:]
    __shared__ float s_wmax[2];
    __shared__ float s_cw[128];              // compositing weights
    __shared__ float s_part[8 * 16];

    // ---- weight B-fragments (coalesced, L1/L2-resident; issue early) ----
    bf16x8 bw0[4], bw1[8];
    #pragma unroll
    for (int i = 0; i < 4; ++i) bw0[i] = *(const bf16x8*)(wsf + i * 512 + lane * 8);
    #pragma unroll
    for (int i = 0; i < 8; ++i) bw1[i] = *(const bf16x8*)(wsf + 2048 + i * 512 + lane * 8);

    // ---- stage: coalesced x read, random gather, LDS writes ----
    #pragma unroll
    for (int e0 = 0; e0 < 768; e0 += 512) {
        int e = e0 + t;
        if (e < 768) {
            int xv = x[(size_t)b * 768 + e];
            int point = e / 6;
            int level = e - point * 6;
            float4 v = *(const float4*)(gw + (size_t)xv * 4);
            s_sigl[e] = fminf(fmaxf(v.x, 0.0f), 1.0f);
            unsigned short* a = A0 + point * 40 + level * 3;
            a[0] = f2b(v.y); a[1] = f2b(v.z); a[2] = f2b(v.w);
        }
    }
    if (t < 128) {  // zero-pad geo cols 18..31
        unsigned short* a = A0 + t * 40;
        *(unsigned int*)(a + 18) = 0u;
        *(uint2*)(a + 20) = make_uint2(0u, 0u);
        *(uint2*)(a + 24) = make_uint2(0u, 0u);
        *(uint2*)(a + 28) = make_uint2(0u, 0u);
    }
    if (t < 64) {   // per-ray direction contribution (fp32)
        float acc = b0[t];
        const float* db = dvec + (size_t)b * 16;
        #pragma unroll
        for (int i = 0; i < 16; ++i) acc = fmaf(db[i], W0[i * 64 + t], acc);
        s_dirW[t] = acc;
    }
    __syncthreads();

    // ---- sigma: product of 6 clipped densities, max over ray, normalize ----
    float sigma0 = 0.0f;
    if (t < 128) {
        float p = 1.0f;
        #pragma unroll
        for (int l = 0; l < 6; ++l) p *= s_sigl[t * 6 + l];
        sigma0 = p + 1e-4f;
        float m = sigma0;
        #pragma unroll
        for (int off = 32; off; off >>= 1) m = fmaxf(m, __shfl_xor(m, off));
        if (lane == 0) s_wmax[w] = m;
    }
    __syncthreads();
    if (t < 128) {
        float maxv  = fmaxf(s_wmax[0], s_wmax[1]);
        float sigma = sigma0 / maxv;
        out_sigma[(size_t)b * 128 + t] = sigma;
        float cw;
        if (t == 0) cw = sigma;
        else {
            float pp = 1.0f;
            #pragma unroll
            for (int l = 0; l < 6; ++l) pp *= s_sigl[(t - 1) * 6 + l];
            float sprev = (pp + 1e-4f) / maxv;
            cw = (1.0f - sprev) * sigma;
        }
        s_cw[t] = cw;
    }

    // ---- layer 0 (geo part via MFMA, dir part as fp32 C-init) ----
    const int row = w * 16 + l15;
    bf16x8 a0 = *(const bf16x8*)(A0 + row * 40 + quad * 8);
    floatx4 acc0[4];
    #pragma unroll
    for (int nt = 0; nt < 4; ++nt) {
        float dw = s_dirW[nt * 16 + l15];
        acc0[nt] = (floatx4){dw, dw, dw, dw};
        acc0[nt] = __builtin_amdgcn_mfma_f32_16x16x32_bf16(a0, bw0[nt], acc0[nt], 0, 0, 0);
    }
    // relu -> bf16 -> LDS in A-layout (wave-private rows; in-wave LDS order is safe)
    #pragma unroll
    for (int nt = 0; nt < 4; ++nt)
        #pragma unroll
        for (int r = 0; r < 4; ++r) {
            int pr = w * 16 + quad * 4 + r;
            H1[pr * 72 + nt * 16 + l15] = f2b(fmaxf(acc0[nt][r], 0.0f));
        }

    // ---- layer 1 (64x64) ----
    bf16x8 a1a = *(const bf16x8*)(H1 + row * 72 + quad * 8);
    bf16x8 a1b = *(const bf16x8*)(H1 + row * 72 + 32 + quad * 8);
    floatx4 acc1[4];
    #pragma unroll
    for (int nt = 0; nt < 4; ++nt) {
        float bb = b1[nt * 16 + l15];
        acc1[nt] = (floatx4){bb, bb, bb, bb};
        acc1[nt] = __builtin_amdgcn_mfma_f32_16x16x32_bf16(a1a, bw1[nt],     acc1[nt], 0, 0, 0);
        acc1[nt] = __builtin_amdgcn_mfma_f32_16x16x32_bf16(a1b, bw1[4 + nt], acc1[nt], 0, 0, 0);
    }
    // relu -> bf16 -> LDS (overwrite own rows)
    #pragma unroll
    for (int nt = 0; nt < 4; ++nt)
        #pragma unroll
        for (int r = 0; r < 4; ++r) {
            int pr = w * 16 + quad * 4 + r;
            H1[pr * 72 + nt * 16 + l15] = f2b(fmaxf(acc1[nt][r], 0.0f));
        }

    // ---- layer 2 (64->3, N padded to 16) ----
    bf16x8 bw2a = *(const bf16x8*)(wsf + 6144 + lane * 8);
    bf16x8 bw2b = *(const bf16x8*)(wsf + 6144 + 512 + lane * 8);
    bf16x8 a2a = *(const bf16x8*)(H1 + row * 72 + quad * 8);
    bf16x8 a2b = *(const bf16x8*)(H1 + row * 72 + 32 + quad * 8);
    float bias2 = (l15 < 3) ? b2[l15] : 0.0f;
    floatx4 acc2 = (floatx4){bias2, bias2, bias2, bias2};
    acc2 = __builtin_amdgcn_mfma_f32_16x16x32_bf16(a2a, bw2a, acc2, 0, 0, 0);
    acc2 = __builtin_amdgcn_mfma_f32_16x16x32_bf16(a2b, bw2b, acc2, 0, 0, 0);

    __syncthreads();  // s_cw ready
    // sigmoid + compositing weight + reduce over the wave's 16 points
    float sum = 0.0f;
    #pragma unroll
    for (int r = 0; r < 4; ++r) {
        float col = 1.0f / (1.0f + __expf(-acc2[r]));
        float cw  = s_cw[w * 16 + quad * 4 + r];
        sum += cw * col;
    }
    sum += __shfl_xor(sum, 16);
    sum += __shfl_xor(sum, 32);
    if (lane < 16) s_part[w * 16 + lane] = sum;   // col = lane
    __syncthreads();
    if (t < 3) {
        float o = 0.0f;
        #pragma unroll
        for (int ww = 0; ww < 8; ++ww) o += s_part[ww * 16 + t];
        out_color[(size_t)b * 3 + t] = o;
    }
}

extern "C" void kernel_launch(void* const* d_in, const int* in_sizes, int n_in,
                              void* d_out, int out_size, void* d_ws, size_t ws_size,
                              hipStream_t stream) {
    const int*   x    = (const int*)d_in[0];
    const float* dvec = (const float*)d_in[1];
    const float* gw   = (const float*)d_in[2];
    const float* W0   = (const float*)d_in[3];
    const float* b0   = (const float*)d_in[4];
    const float* W1   = (const float*)d_in[5];
    const float* b1   = (const float*)d_in[6];
    const float* W2   = (const float*)d_in[7];
    const float* b2   = (const float*)d_in[8];

    const int B = in_sizes[1] / 16;                       // d is (B, 16)
    float* out_sigma = (float*)d_out;                     // (B, 128)
    float* out_color = (float*)d_out + (size_t)B * 128;   // (B, 3)
    unsigned short* wsf = (unsigned short*)d_ws;          // 14336 B used

    build_frags<<<14, 512, 0, stream>>>(W0, W1, W2, wsf);
    surf_main<<<B, 512, 0, stream>>>(x, dvec, gw, W0, b0, b1, b2, wsf,
                                     out_sigma, out_color);
}